// Round 1
// baseline (491.951 us; speedup 1.0000x reference)
//
#include <hip/hip_runtime.h>
#include <hip/hip_bf16.h>

#define DIMF 512
#define NHEAD 8
#define DHEAD 64
#define BATCH 2
#define SEQN 2048
#define SEQM 2048
#define QS 68   // padded LDS row stride (floats), 16B-aligned rows, breaks pow2 banks

// ---------------------------------------------------------------------------
// Tiled fp32 GEMM: Out = X @ W^T + bias.  X:[R,512], W:[512,512] row-major
// (out_col, k) -- i.e. k contiguous, same as X. 64x64 tile, 256 thr, 4x4/thr.
// mode 0: scatter to [B][H][seq][Dh] (q/k/v).  mode 1: row-major [R,512].
// ---------------------------------------------------------------------------
__device__ __forceinline__
void gemm64(const float* __restrict__ X, const float* __restrict__ W,
            const float* __restrict__ bias, float* __restrict__ Out, int mode)
{
    __shared__ float Xs[16][QS];   // k-major: Xs[k][r]
    __shared__ float Ws[16][QS];   // k-major: Ws[k][j]
    const int tid = threadIdx.x;
    const int tx = tid & 15, ty = tid >> 4;
    const int r0 = blockIdx.x * 64, j0 = blockIdx.y * 64;
    const int lr = tid >> 2;            // 0..63
    const int lk = (tid & 3) << 2;      // 0,4,8,12
    float acc[4][4] = {};

    for (int k0 = 0; k0 < DIMF; k0 += 16) {
        float4 xv = *(const float4*)&X[(size_t)(r0 + lr) * DIMF + k0 + lk];
        float4 wv = *(const float4*)&W[(size_t)(j0 + lr) * DIMF + k0 + lk];
        __syncthreads();   // previous tile's compute done before overwrite
        Xs[lk+0][lr] = xv.x; Xs[lk+1][lr] = xv.y; Xs[lk+2][lr] = xv.z; Xs[lk+3][lr] = xv.w;
        Ws[lk+0][lr] = wv.x; Ws[lk+1][lr] = wv.y; Ws[lk+2][lr] = wv.z; Ws[lk+3][lr] = wv.w;
        __syncthreads();
        #pragma unroll
        for (int kk = 0; kk < 16; ++kk) {
            float4 av = *(const float4*)&Xs[kk][ty << 2];
            float4 bv = *(const float4*)&Ws[kk][tx << 2];
            const float* ap = &av.x; const float* bp = &bv.x;
            #pragma unroll
            for (int i = 0; i < 4; ++i)
                #pragma unroll
                for (int j = 0; j < 4; ++j)
                    acc[i][j] = fmaf(ap[i], bp[j], acc[i][j]);
        }
    }

    float4 bl = *(const float4*)&bias[j0 + (tx << 2)];
    const float* blp = &bl.x;
    #pragma unroll
    for (int i = 0; i < 4; ++i) {
        int rr = r0 + (ty << 2) + i;
        float4 o4;
        o4.x = acc[i][0] + blp[0];
        o4.y = acc[i][1] + blp[1];
        o4.z = acc[i][2] + blp[2];
        o4.w = acc[i][3] + blp[3];
        if (mode == 0) {
            int b = rr >> 11;              // rr = b*2048 + n
            int n = rr & (SEQN - 1);
            int h = j0 >> 6;               // tile col block == head
            *(float4*)&Out[(((size_t)(b * NHEAD + h) * SEQN) + n) * DHEAD + (tx << 2)] = o4;
        } else {
            *(float4*)&Out[(size_t)rr * DIMF + j0 + (tx << 2)] = o4;
        }
    }
}

__global__ __launch_bounds__(256)
void qkv_proj(const float* __restrict__ x, const float* __restrict__ src,
              const float* __restrict__ Wq, const float* __restrict__ bq,
              const float* __restrict__ Wk, const float* __restrict__ bk,
              const float* __restrict__ Wv, const float* __restrict__ bv,
              float* __restrict__ qw, float* __restrict__ kw, float* __restrict__ vw)
{
    const int z = blockIdx.z;
    const float* X = (z == 0) ? x  : src;
    const float* W = (z == 0) ? Wq : (z == 1) ? Wk : Wv;
    const float* B = (z == 0) ? bq : (z == 1) ? bk : bv;
    float*       O = (z == 0) ? qw : (z == 1) ? kw : vw;
    gemm64(X, W, B, O, 0);
}

__global__ __launch_bounds__(256)
void out_proj(const float* __restrict__ agg, const float* __restrict__ Wm,
              const float* __restrict__ bm, float* __restrict__ out)
{
    gemm64(agg, Wm, bm, out, 1);
}

// ---------------------------------------------------------------------------
// Flash attention, fp32. One block = (b, h, 64 q-rows). 256 threads, 4x4/thr.
// q/k/v in [B][H][seq][64] layout; agg written [B][N][512].
// softmax over m with mask (int32, nonzero = keep). -1e30 sentinel; p guarded
// by mask so an all-masked tile cannot yield exp(0)=1.
// ---------------------------------------------------------------------------
__global__ __launch_bounds__(256)
void flash_attn(const float* __restrict__ q, const float* __restrict__ k,
                const float* __restrict__ v, const int* __restrict__ mask,
                float* __restrict__ agg)
{
    __shared__ float Qs[64 * QS];
    __shared__ float Ks[64 * QS];
    __shared__ float Vs[64 * QS];
    __shared__ float Ps[64 * QS];
    __shared__ float red[64 * 17];       // stride 17: conflict-light reductions
    __shared__ float row_m[64], row_l[64], row_al[64], row_nm[64];
    __shared__ int   msk[64];

    const int tid = threadIdx.x;
    const int tx = tid & 15, ty = tid >> 4;
    const int ry = ty << 2, dx = tx << 2;
    const int qt = blockIdx.x, h = blockIdx.y, b = blockIdx.z;
    const int n0 = qt * 64;

    const float* qb = q + ((size_t)(b * NHEAD + h) * SEQN + n0) * DHEAD;
    const float* kb = k + (size_t)(b * NHEAD + h) * SEQM * DHEAD;
    const float* vb = v + (size_t)(b * NHEAD + h) * SEQM * DHEAD;

    // load Q tile (64x64 floats = 1024 float4, 4 per thread), coalesced
    #pragma unroll
    for (int i = 0; i < 4; ++i) {
        int e = tid + (i << 8);
        int r = e >> 4, c = (e & 15) << 2;
        *(float4*)&Qs[r * QS + c] = *(const float4*)&qb[(size_t)r * DHEAD + c];
    }
    if (tid < 64) { row_m[tid] = -1e30f; row_l[tid] = 0.f; }

    float o[4][4] = {};

    for (int mt = 0; mt < SEQM / 64; ++mt) {
        const int m0 = mt << 6;
        __syncthreads();   // prior iteration's LDS reads done before overwrite
        #pragma unroll
        for (int i = 0; i < 4; ++i) {
            int e = tid + (i << 8);
            int r = e >> 4, c = (e & 15) << 2;
            *(float4*)&Ks[r * QS + c] = *(const float4*)&kb[(size_t)(m0 + r) * DHEAD + c];
            *(float4*)&Vs[r * QS + c] = *(const float4*)&vb[(size_t)(m0 + r) * DHEAD + c];
        }
        if (tid < 64) msk[tid] = mask[b * SEQM + m0 + tid];
        __syncthreads();

        // S = (Q K^T) * scale, masked
        float s[4][4] = {};
        for (int c = 0; c < DHEAD; c += 4) {
            float4 qa[4], kv4[4];
            #pragma unroll
            for (int i = 0; i < 4; ++i) qa[i]  = *(const float4*)&Qs[(ry + i) * QS + c];
            #pragma unroll
            for (int j = 0; j < 4; ++j) kv4[j] = *(const float4*)&Ks[(dx + j) * QS + c];
            #pragma unroll
            for (int i = 0; i < 4; ++i) {
                const float* ap = &qa[i].x;
                #pragma unroll
                for (int j = 0; j < 4; ++j) {
                    const float* bp = &kv4[j].x;
                    s[i][j] = fmaf(ap[0], bp[0],
                              fmaf(ap[1], bp[1],
                              fmaf(ap[2], bp[2],
                              fmaf(ap[3], bp[3], s[i][j]))));
                }
            }
        }
        #pragma unroll
        for (int i = 0; i < 4; ++i) {
            float tm = -1e30f;
            #pragma unroll
            for (int j = 0; j < 4; ++j) {
                float sv = msk[dx + j] ? s[i][j] * 0.125f : -1e30f;
                s[i][j] = sv;
                tm = fmaxf(tm, sv);
            }
            red[(ry + i) * 17 + tx] = tm;
        }
        __syncthreads();
        if (tid < 64) {
            float mx = row_m[tid];
            #pragma unroll
            for (int t = 0; t < 16; ++t) mx = fmaxf(mx, red[tid * 17 + t]);
            row_al[tid] = __expf(row_m[tid] - mx);   // exp(-huge)=0 when mx grew
            row_nm[tid] = mx;
            row_m[tid]  = mx;
        }
        __syncthreads();
        // P = exp(S - m_new); write to LDS + partial row sums
        #pragma unroll
        for (int i = 0; i < 4; ++i) {
            float nm = row_nm[ry + i];
            float4 p4;
            p4.x = msk[dx + 0] ? __expf(s[i][0] - nm) : 0.f;
            p4.y = msk[dx + 1] ? __expf(s[i][1] - nm) : 0.f;
            p4.z = msk[dx + 2] ? __expf(s[i][2] - nm) : 0.f;
            p4.w = msk[dx + 3] ? __expf(s[i][3] - nm) : 0.f;
            *(float4*)&Ps[(ry + i) * QS + dx] = p4;
            red[(ry + i) * 17 + tx] = p4.x + p4.y + p4.z + p4.w;
        }
        __syncthreads();
        if (tid < 64) {
            float sm = 0.f;
            #pragma unroll
            for (int t = 0; t < 16; ++t) sm += red[tid * 17 + t];
            row_l[tid] = row_l[tid] * row_al[tid] + sm;
        }
        // O = O*alpha + P V
        #pragma unroll
        for (int i = 0; i < 4; ++i) {
            float a = row_al[ry + i];
            #pragma unroll
            for (int j = 0; j < 4; ++j) o[i][j] *= a;
        }
        for (int mc = 0; mc < 64; mc += 4) {
            float4 pv[4], vv[4];
            #pragma unroll
            for (int i = 0; i < 4; ++i)  pv[i]  = *(const float4*)&Ps[(ry + i) * QS + mc];
            #pragma unroll
            for (int t2 = 0; t2 < 4; ++t2) vv[t2] = *(const float4*)&Vs[(mc + t2) * QS + dx];
            #pragma unroll
            for (int i = 0; i < 4; ++i) {
                const float* pp = &pv[i].x;
                #pragma unroll
                for (int j = 0; j < 4; ++j) {
                    float a2 = o[i][j];
                    a2 = fmaf(pp[0], (&vv[0].x)[j], a2);
                    a2 = fmaf(pp[1], (&vv[1].x)[j], a2);
                    a2 = fmaf(pp[2], (&vv[2].x)[j], a2);
                    a2 = fmaf(pp[3], (&vv[3].x)[j], a2);
                    o[i][j] = a2;
                }
            }
        }
    }
    __syncthreads();   // row_l final before everyone reads it
    #pragma unroll
    for (int i = 0; i < 4; ++i) {
        float inv = 1.f / row_l[ry + i];
        float4 o4 = make_float4(o[i][0] * inv, o[i][1] * inv, o[i][2] * inv, o[i][3] * inv);
        int n = n0 + ry + i;
        *(float4*)&agg[((size_t)b * SEQN + n) * DIMF + h * DHEAD + dx] = o4;
    }
}

extern "C" void kernel_launch(void* const* d_in, const int* in_sizes, int n_in,
                              void* d_out, int out_size, void* d_ws, size_t ws_size,
                              hipStream_t stream)
{
    (void)in_sizes; (void)n_in; (void)out_size; (void)ws_size;
    const float* x      = (const float*)d_in[0];
    const float* source = (const float*)d_in[1];
    const int*   mask   = (const int*)  d_in[2];   // bool -> int32 per harness
    const float* Wq = (const float*)d_in[3]; const float* bq = (const float*)d_in[4];
    const float* Wk = (const float*)d_in[5]; const float* bk = (const float*)d_in[6];
    const float* Wv = (const float*)d_in[7]; const float* bv = (const float*)d_in[8];
    const float* Wm = (const float*)d_in[9]; const float* bm = (const float*)d_in[10];
    float* out = (float*)d_out;

    float* ws   = (float*)d_ws;
    const size_t SZ = (size_t)BATCH * SEQN * DIMF;   // 2,097,152 floats each
    float* qw   = ws;
    float* kw   = ws + SZ;
    float* vw   = ws + 2 * SZ;
    float* aggw = ws + 3 * SZ;

    dim3 gproj(64, 8, 3);   // (4096/64 row tiles, 512/64 col tiles, q/k/v)
    qkv_proj<<<gproj, 256, 0, stream>>>(x, source, Wq, bq, Wk, bk, Wv, bv, qw, kw, vw);

    dim3 gattn(SEQN / 64, NHEAD, BATCH);   // (32, 8, 2)
    flash_attn<<<gattn, 256, 0, stream>>>(qw, kw, vw, mask, aggw);

    dim3 gout(64, 8);
    out_proj<<<gout, 256, 0, stream>>>(aggw, Wm, bm, out);
}

// Round 2
// 264.465 us; speedup vs baseline: 1.8602x; 1.8602x over previous
//
#include <hip/hip_runtime.h>
#include <hip/hip_bf16.h>

#define DIMF 512
#define NHEAD 8
#define DHEAD 64
#define BATCH 2
#define SEQN 2048
#define SEQM 2048
#define QS 68     // fp32 GEMM LDS row stride
#define PKS 72    // attention LDS row stride in bf16 elems (16B-aligned, breaks pow2)

typedef unsigned short u16;
typedef __attribute__((ext_vector_type(8))) short bf16x8;
typedef __attribute__((ext_vector_type(4))) float f32x4;

static __device__ __forceinline__ u16 f2bf(float f) {
    unsigned u = __float_as_uint(f);
    u += 0x7FFF + ((u >> 16) & 1);      // RNE
    return (u16)(u >> 16);
}

// ---------------------------------------------------------------------------
// Tiled fp32 GEMM: Out = X @ W^T + bias.  64x64 tile, 256 thr, 4x4/thr.
// mode 0: q -> bf16 [B][H][n][d], values * 0.125 (softmax scale folded in)
// mode 1: k -> bf16 [B][H][m][d]
// mode 2: v -> bf16 TRANSPOSED [B][H][d][m]
// mode 3: fp32 row-major [R,512]
// ---------------------------------------------------------------------------
__device__ __forceinline__
void gemm64(const float* __restrict__ X, const float* __restrict__ W,
            const float* __restrict__ bias, void* __restrict__ Out, int mode)
{
    __shared__ float Xs[16][QS];
    __shared__ float Ws[16][QS];
    const int tid = threadIdx.x;
    const int tx = tid & 15, ty = tid >> 4;
    const int r0 = blockIdx.x * 64, j0 = blockIdx.y * 64;
    const int lr = tid >> 2;
    const int lk = (tid & 3) << 2;
    float acc[4][4] = {};

    for (int k0 = 0; k0 < DIMF; k0 += 16) {
        float4 xv = *(const float4*)&X[(size_t)(r0 + lr) * DIMF + k0 + lk];
        float4 wv = *(const float4*)&W[(size_t)(j0 + lr) * DIMF + k0 + lk];
        __syncthreads();
        Xs[lk+0][lr] = xv.x; Xs[lk+1][lr] = xv.y; Xs[lk+2][lr] = xv.z; Xs[lk+3][lr] = xv.w;
        Ws[lk+0][lr] = wv.x; Ws[lk+1][lr] = wv.y; Ws[lk+2][lr] = wv.z; Ws[lk+3][lr] = wv.w;
        __syncthreads();
        #pragma unroll
        for (int kk = 0; kk < 16; ++kk) {
            float4 av = *(const float4*)&Xs[kk][ty << 2];
            float4 bv = *(const float4*)&Ws[kk][tx << 2];
            const float* ap = &av.x; const float* bp = &bv.x;
            #pragma unroll
            for (int i = 0; i < 4; ++i)
                #pragma unroll
                for (int j = 0; j < 4; ++j)
                    acc[i][j] = fmaf(ap[i], bp[j], acc[i][j]);
        }
    }

    float4 bl = *(const float4*)&bias[j0 + (tx << 2)];
    const float* blp = &bl.x;
    const int h = j0 >> 6;
    #pragma unroll
    for (int i = 0; i < 4; ++i) {
        int rr = r0 + (ty << 2) + i;
        int b = rr >> 11;
        int n = rr & (SEQN - 1);
        float o[4];
        #pragma unroll
        for (int j = 0; j < 4; ++j) o[j] = acc[i][j] + blp[j];
        if (mode == 0) {
            ushort4 u4 = make_ushort4(f2bf(o[0]*0.125f), f2bf(o[1]*0.125f),
                                      f2bf(o[2]*0.125f), f2bf(o[3]*0.125f));
            *(ushort4*)&((u16*)Out)[(((size_t)(b*NHEAD+h)*SEQN)+n)*DHEAD + (tx<<2)] = u4;
        } else if (mode == 1) {
            ushort4 u4 = make_ushort4(f2bf(o[0]), f2bf(o[1]), f2bf(o[2]), f2bf(o[3]));
            *(ushort4*)&((u16*)Out)[(((size_t)(b*NHEAD+h)*SEQN)+n)*DHEAD + (tx<<2)] = u4;
        } else if (mode == 2) {
            u16* ow = (u16*)Out;
            #pragma unroll
            for (int jj = 0; jj < 4; ++jj) {
                int d = (tx << 2) + jj;
                ow[((size_t)(b*NHEAD+h)*DHEAD + d)*SEQM + n] = f2bf(o[jj]);
            }
        } else {
            *(float4*)&((float*)Out)[(size_t)rr * DIMF + j0 + (tx << 2)] =
                make_float4(o[0], o[1], o[2], o[3]);
        }
    }
}

__global__ __launch_bounds__(256)
void qkv_proj(const float* __restrict__ x, const float* __restrict__ src,
              const float* __restrict__ Wq, const float* __restrict__ bq,
              const float* __restrict__ Wk, const float* __restrict__ bk,
              const float* __restrict__ Wv, const float* __restrict__ bv,
              u16* __restrict__ qw, u16* __restrict__ kw, u16* __restrict__ vtw)
{
    const int z = blockIdx.z;
    const float* X = (z == 0) ? x  : src;
    const float* W = (z == 0) ? Wq : (z == 1) ? Wk : Wv;
    const float* B = (z == 0) ? bq : (z == 1) ? bk : bv;
    void*        O = (z == 0) ? (void*)qw : (z == 1) ? (void*)kw : (void*)vtw;
    gemm64(X, W, B, O, z);
}

__global__ __launch_bounds__(256)
void out_proj(const float* __restrict__ agg, const float* __restrict__ Wm,
              const float* __restrict__ bm, float* __restrict__ out)
{
    gemm64(agg, Wm, bm, (void*)out, 3);
}

// ---------------------------------------------------------------------------
// MFMA flash attention (bf16 inputs, fp32 accum).
// Block = (b, h, 64 q-rows), 4 waves; wave owns 16 q-rows.
// S^T = K . Q^T per 64-m tile -> C layout: row = m_kv(16*sub+quad*4+r), col = q(l15)
// => softmax state scalar-per-lane (q-row = l15). P^T regs are 4 consecutive
// m_kv per (sub) -> packed b64 writes into Ps[q][m_kv]; A-frag reads contiguous.
// V staged transposed (Vts[d][m]) so PV B-frags are contiguous 16B reads.
// Mask via one __ballot per tile.
// ---------------------------------------------------------------------------
__global__ __launch_bounds__(256)
void flash_attn_mfma(const u16* __restrict__ q, const u16* __restrict__ k,
                     const u16* __restrict__ vt, const int* __restrict__ mask,
                     float* __restrict__ agg)
{
    __shared__ u16 Ks[64 * PKS];        // [m_local][d]
    __shared__ u16 Vts[64 * PKS];       // [d][m_local]
    __shared__ u16 Ps[4][16 * PKS];     // per-wave [q_local][m_local]

    const int tid  = threadIdx.x;
    const int wave = tid >> 6;
    const int lane = tid & 63;
    const int l15  = lane & 15;
    const int quad = lane >> 4;
    const int qt = blockIdx.x, h = blockIdx.y, b = blockIdx.z;
    const int n0 = qt * 64;
    const size_t hoff = (size_t)(b * NHEAD + h) * (size_t)SEQM * DHEAD;
    const u16* kb = k  + hoff;
    const u16* vb = vt + hoff;
    const int* mg = mask + b * SEQM;

    // Q B-fragments (pre-scaled by 1/8): B[k=d][n=q]; lane: q = n0+wave*16+l15
    bf16x8 qf[2];
    {
        const u16* qp = q + hoff + (size_t)(n0 + wave * 16 + l15) * DHEAD + quad * 8;
        qf[0] = *(const bf16x8*)qp;
        qf[1] = *(const bf16x8*)(qp + 32);
    }

    f32x4 O[4] = {};                  // O[sd]: q-row = quad*4+r, d = 16*sd+l15
    float m_run = -1e30f, l_run = 0.f; // per-lane, q-row = l15

    for (int mt = 0; mt < SEQM / 64; ++mt) {
        const int m0 = mt * 64;
        unsigned long long mbits = __ballot(mg[m0 + lane] != 0);
        __syncthreads();
        #pragma unroll
        for (int i = 0; i < 2; ++i) {
            int c = tid + (i << 8);
            int r = c >> 3, co = (c & 7) << 3;
            *(bf16x8*)&Ks[r * PKS + co]  = *(const bf16x8*)&kb[(size_t)(m0 + r) * DHEAD + co];
            *(bf16x8*)&Vts[r * PKS + co] = *(const bf16x8*)&vb[(size_t)r * SEQM + m0 + co];
        }
        __syncthreads();

        // S^T: st[sub], rows m = 16*sub+quad*4+r, col q = l15
        f32x4 st[4] = {};
        #pragma unroll
        for (int sub = 0; sub < 4; ++sub) {
            #pragma unroll
            for (int c = 0; c < 2; ++c) {
                bf16x8 af = *(const bf16x8*)&Ks[(16 * sub + l15) * PKS + 32 * c + quad * 8];
                st[sub] = __builtin_amdgcn_mfma_f32_16x16x32_bf16(af, qf[c], st[sub], 0, 0, 0);
            }
        }

        // mask + row max (row = q = l15)
        float mx = -1e30f;
        float sv[4][4];
        #pragma unroll
        for (int sub = 0; sub < 4; ++sub)
            #pragma unroll
            for (int r = 0; r < 4; ++r) {
                int bit = (int)((mbits >> (16*sub + 4*quad + r)) & 1ULL);
                float xv = bit ? st[sub][r] : -1e30f;
                sv[sub][r] = xv;
                mx = fmaxf(mx, xv);
            }
        mx = fmaxf(mx, __shfl_xor(mx, 16));
        mx = fmaxf(mx, __shfl_xor(mx, 32));
        const float mnew = fmaxf(m_run, mx);
        const float alpha = __expf(m_run - mnew);
        m_run = mnew;

        // P = exp(S - m), masked; row partial sums; pack bf16
        float psum = 0.f;
        u16 pb[4][4];
        #pragma unroll
        for (int sub = 0; sub < 4; ++sub)
            #pragma unroll
            for (int r = 0; r < 4; ++r) {
                int bit = (int)((mbits >> (16*sub + 4*quad + r)) & 1ULL);
                float p = __expf(sv[sub][r] - mnew);
                p = bit ? p : 0.f;
                psum += p;
                pb[sub][r] = f2bf(p);
            }
        psum += __shfl_xor(psum, 16);
        psum += __shfl_xor(psum, 32);
        l_run = l_run * alpha + psum;

        // P^T -> Ps[q=l15][m_kv], 4 consecutive m per (sub): b64 writes
        #pragma unroll
        for (int sub = 0; sub < 4; ++sub) {
            ushort4 w4 = make_ushort4(pb[sub][0], pb[sub][1], pb[sub][2], pb[sub][3]);
            *(ushort4*)&Ps[wave][l15 * PKS + 16 * sub + 4 * quad] = w4;
        }

        // O rescale: alpha lives at lane l15 = q-row; O rows are quad*4+r
        float ar[4];
        #pragma unroll
        for (int r = 0; r < 4; ++r) ar[r] = __shfl(alpha, quad * 4 + r);
        #pragma unroll
        for (int sd = 0; sd < 4; ++sd)
            #pragma unroll
            for (int r = 0; r < 4; ++r) O[sd][r] *= ar[r];

        // PV: A = P (rows q), B = V (Vts rows d)
        #pragma unroll
        for (int c = 0; c < 2; ++c) {
            bf16x8 pf = *(const bf16x8*)&Ps[wave][l15 * PKS + 32 * c + quad * 8];
            #pragma unroll
            for (int sd = 0; sd < 4; ++sd) {
                bf16x8 vf = *(const bf16x8*)&Vts[(16 * sd + l15) * PKS + 32 * c + quad * 8];
                O[sd] = __builtin_amdgcn_mfma_f32_16x16x32_bf16(pf, vf, O[sd], 0, 0, 0);
            }
        }
    }

    // epilogue: 1/l per q-row, scatter fp32 agg[b][n][h*64+d]
    float lr4[4];
    #pragma unroll
    for (int r = 0; r < 4; ++r) lr4[r] = __shfl(l_run, quad * 4 + r);
    #pragma unroll
    for (int r = 0; r < 4; ++r) {
        const int n = n0 + wave * 16 + quad * 4 + r;
        const float inv = 1.f / lr4[r];
        float* ag = agg + ((size_t)b * SEQN + n) * DIMF + h * DHEAD + l15;
        #pragma unroll
        for (int sd = 0; sd < 4; ++sd)
            ag[16 * sd] = O[sd][r] * inv;
    }
}

extern "C" void kernel_launch(void* const* d_in, const int* in_sizes, int n_in,
                              void* d_out, int out_size, void* d_ws, size_t ws_size,
                              hipStream_t stream)
{
    (void)in_sizes; (void)n_in; (void)out_size; (void)ws_size;
    const float* x      = (const float*)d_in[0];
    const float* source = (const float*)d_in[1];
    const int*   mask   = (const int*)  d_in[2];
    const float* Wq = (const float*)d_in[3]; const float* bq = (const float*)d_in[4];
    const float* Wk = (const float*)d_in[5]; const float* bk = (const float*)d_in[6];
    const float* Wv = (const float*)d_in[7]; const float* bv = (const float*)d_in[8];
    const float* Wm = (const float*)d_in[9]; const float* bm = (const float*)d_in[10];
    float* out = (float*)d_out;

    const size_t SZ = (size_t)BATCH * SEQN * DIMF;  // 2,097,152 elems
    float* aggw = (float*)d_ws;                     // fp32 [B][N][512]
    u16*   qw   = (u16*)(aggw + SZ);                // bf16 [B][H][n][d] (x0.125)
    u16*   kw   = qw + SZ;                          // bf16 [B][H][m][d]
    u16*   vtw  = kw + SZ;                          // bf16 [B][H][d][m]

    dim3 gproj(64, 8, 3);
    qkv_proj<<<gproj, 256, 0, stream>>>(x, source, Wq, bq, Wk, bk, Wv, bv, qw, kw, vtw);

    dim3 gattn(SEQN / 64, NHEAD, BATCH);
    flash_attn_mfma<<<gattn, 256, 0, stream>>>(qw, kw, vtw, mask, aggw);

    dim3 gout(64, 8);
    out_proj<<<gout, 256, 0, stream>>>(aggw, Wm, bm, out);
}

// Round 3
// 171.315 us; speedup vs baseline: 2.8716x; 1.5437x over previous
//
#include <hip/hip_runtime.h>
#include <hip/hip_bf16.h>

#define DIMF 512
#define NHEAD 8
#define DHEAD 64
#define BATCH 2
#define SEQN 2048
#define SEQM 2048
#define PKS 72    // attention LDS row stride in bf16 elems (16B-aligned, breaks pow2)

typedef unsigned short u16;
typedef __attribute__((ext_vector_type(8))) short bf16x8;
typedef __attribute__((ext_vector_type(4))) float f32x4;

static __device__ __forceinline__ u16 f2bf(float f) {
    unsigned u = __float_as_uint(f);
    u += 0x7FFF + ((u >> 16) & 1);      // RNE
    return (u16)(u >> 16);
}

static __device__ __forceinline__
void load16(const u16* g, u16* l) {
    __builtin_amdgcn_global_load_lds(
        (const __attribute__((address_space(1))) void*)g,
        (__attribute__((address_space(3))) void*)l,
        16, 0, 0);
}

// ---------------------------------------------------------------------------
// fp32 -> bf16 convert: y selects array {x, source, Wq, Wk, Wv, Wm}
// ---------------------------------------------------------------------------
__global__ __launch_bounds__(256)
void cvt_bf16(const float* __restrict__ x, const float* __restrict__ src,
              const float* __restrict__ wq, const float* __restrict__ wk,
              const float* __restrict__ wv, const float* __restrict__ wm,
              u16* __restrict__ xb, u16* __restrict__ srcb,
              u16* __restrict__ wqb, u16* __restrict__ wkb,
              u16* __restrict__ wvb, u16* __restrict__ wmb)
{
    const float* in; u16* out; int n;
    switch (blockIdx.y) {
        case 0: in = x;   out = xb;   n = BATCH * SEQN * DIMF; break;
        case 1: in = src; out = srcb; n = BATCH * SEQM * DIMF; break;
        case 2: in = wq;  out = wqb;  n = DIMF * DIMF; break;
        case 3: in = wk;  out = wkb;  n = DIMF * DIMF; break;
        case 4: in = wv;  out = wvb;  n = DIMF * DIMF; break;
        default:in = wm;  out = wmb;  n = DIMF * DIMF; break;
    }
    int i = (blockIdx.x * 256 + threadIdx.x) * 4;
    if (i >= n) return;
    float4 v = *(const float4*)&in[i];
    *(ushort4*)&out[i] = make_ushort4(f2bf(v.x), f2bf(v.y), f2bf(v.z), f2bf(v.w));
}

// ---------------------------------------------------------------------------
// bf16 MFMA GEMM: Out = X(4096x512) @ W^T(512x512) + bias.
// 128x128 tile, 4 waves (2x2), each wave 64x64 = 4x4 frags of 16x16x32.
// global_load_lds width-16 staging into unpadded LDS (lane-contiguous).
// mode 0: q -> bf16 [B][H][n][d], (val+bias)*0.125
// mode 1: k -> bf16 [B][H][m][d]
// mode 2: v -> bf16 transposed [B][H][d][m] (ushort4 along n)
// mode 3: fp32 row-major [4096][512]
// ---------------------------------------------------------------------------
__device__ __forceinline__
void gemm_mfma(const u16* __restrict__ X, const u16* __restrict__ W,
               const float* __restrict__ bias, void* __restrict__ Out, int mode)
{
    __shared__ u16 As[128 * 32];   // 8 KB, row-major [row][32k], 64 B rows
    __shared__ u16 Bs[128 * 32];

    const int tid  = threadIdx.x;
    const int wave = tid >> 6;
    const int lane = tid & 63;
    const int l15  = lane & 15;
    const int quad = lane >> 4;
    const int wm = wave & 1, wn = wave >> 1;
    const int r0 = blockIdx.x * 128, c0 = blockIdx.y * 128;

    const u16* Ab = X + (size_t)r0 * DIMF;
    const u16* Bb = W + (size_t)c0 * DIMF;

    f32x4 acc[4][4] = {};

    for (int k0 = 0; k0 < DIMF; k0 += 32) {
        __syncthreads();
        #pragma unroll
        for (int i = 0; i < 2; ++i) {
            int chunk = i * 256 + tid;          // 16-B chunk id, 512 per tile
            int row = chunk >> 2, kc = (chunk & 3) << 3;
            u16* la = (u16*)((char*)As + i * 4096 + wave * 1024);
            u16* lb = (u16*)((char*)Bs + i * 4096 + wave * 1024);
            load16(Ab + row * DIMF + k0 + kc, la);
            load16(Bb + row * DIMF + k0 + kc, lb);
        }
        __syncthreads();

        bf16x8 af[4], bf[4];
        #pragma unroll
        for (int mi = 0; mi < 4; ++mi)
            af[mi] = *(const bf16x8*)&As[(wm * 64 + mi * 16 + l15) * 32 + quad * 8];
        #pragma unroll
        for (int ni = 0; ni < 4; ++ni)
            bf[ni] = *(const bf16x8*)&Bs[(wn * 64 + ni * 16 + l15) * 32 + quad * 8];
        #pragma unroll
        for (int mi = 0; mi < 4; ++mi)
            #pragma unroll
            for (int ni = 0; ni < 4; ++ni)
                acc[mi][ni] = __builtin_amdgcn_mfma_f32_16x16x32_bf16(
                    af[mi], bf[ni], acc[mi][ni], 0, 0, 0);
    }

    float bb[4];
    #pragma unroll
    for (int ni = 0; ni < 4; ++ni)
        bb[ni] = bias[c0 + wn * 64 + ni * 16 + l15];

    #pragma unroll
    for (int mi = 0; mi < 4; ++mi) {
        const int Rbase = r0 + wm * 64 + mi * 16 + quad * 4;   // +r, r=0..3
        const int b = Rbase >> 11;
        const int nb = Rbase & (SEQN - 1);
        #pragma unroll
        for (int ni = 0; ni < 4; ++ni) {
            const int C = c0 + wn * 64 + ni * 16 + l15;
            const int h = C >> 6, d = C & 63;
            if (mode == 0) {
                u16* ow = (u16*)Out;
                #pragma unroll
                for (int r = 0; r < 4; ++r)
                    ow[(((size_t)(b * NHEAD + h) * SEQN) + nb + r) * DHEAD + d] =
                        f2bf((acc[mi][ni][r] + bb[ni]) * 0.125f);
            } else if (mode == 1) {
                u16* ow = (u16*)Out;
                #pragma unroll
                for (int r = 0; r < 4; ++r)
                    ow[(((size_t)(b * NHEAD + h) * SEQN) + nb + r) * DHEAD + d] =
                        f2bf(acc[mi][ni][r] + bb[ni]);
            } else if (mode == 2) {
                u16* ow = (u16*)Out;
                ushort4 w4 = make_ushort4(f2bf(acc[mi][ni][0] + bb[ni]),
                                          f2bf(acc[mi][ni][1] + bb[ni]),
                                          f2bf(acc[mi][ni][2] + bb[ni]),
                                          f2bf(acc[mi][ni][3] + bb[ni]));
                *(ushort4*)&ow[((size_t)(b * NHEAD + h) * DHEAD + d) * SEQM + nb] = w4;
            } else {
                float* ow = (float*)Out;
                #pragma unroll
                for (int r = 0; r < 4; ++r)
                    ow[(size_t)(Rbase + r) * DIMF + C] = acc[mi][ni][r] + bb[ni];
            }
        }
    }
}

__global__ __launch_bounds__(256)
void qkv_proj(const u16* __restrict__ xb, const u16* __restrict__ srcb,
              const u16* __restrict__ wqb, const float* __restrict__ bq,
              const u16* __restrict__ wkb, const float* __restrict__ bk,
              const u16* __restrict__ wvb, const float* __restrict__ bv,
              u16* __restrict__ qw, u16* __restrict__ kw, u16* __restrict__ vtw)
{
    const int z = blockIdx.z;
    const u16* X = (z == 0) ? xb  : srcb;
    const u16* W = (z == 0) ? wqb : (z == 1) ? wkb : wvb;
    const float* B = (z == 0) ? bq : (z == 1) ? bk : bv;
    void* O = (z == 0) ? (void*)qw : (z == 1) ? (void*)kw : (void*)vtw;
    gemm_mfma(X, W, B, O, z);
}

__global__ __launch_bounds__(256)
void out_proj(const u16* __restrict__ aggb, const u16* __restrict__ wmb,
              const float* __restrict__ bm, float* __restrict__ out)
{
    gemm_mfma(aggb, wmb, bm, (void*)out, 3);
}

// ---------------------------------------------------------------------------
// MFMA flash attention (bf16 inputs, fp32 accum). Unchanged from round 2
// except the epilogue writes bf16 agg.
// ---------------------------------------------------------------------------
__global__ __launch_bounds__(256)
void flash_attn_mfma(const u16* __restrict__ q, const u16* __restrict__ k,
                     const u16* __restrict__ vt, const int* __restrict__ mask,
                     u16* __restrict__ agg)
{
    __shared__ u16 Ks[64 * PKS];        // [m_local][d]
    __shared__ u16 Vts[64 * PKS];       // [d][m_local]
    __shared__ u16 Ps[4][16 * PKS];     // per-wave [q_local][m_local]

    const int tid  = threadIdx.x;
    const int wave = tid >> 6;
    const int lane = tid & 63;
    const int l15  = lane & 15;
    const int quad = lane >> 4;
    const int qt = blockIdx.x, h = blockIdx.y, b = blockIdx.z;
    const int n0 = qt * 64;
    const size_t hoff = (size_t)(b * NHEAD + h) * (size_t)SEQM * DHEAD;
    const u16* kb = k  + hoff;
    const u16* vb = vt + hoff;
    const int* mg = mask + b * SEQM;

    bf16x8 qf[2];
    {
        const u16* qp = q + hoff + (size_t)(n0 + wave * 16 + l15) * DHEAD + quad * 8;
        qf[0] = *(const bf16x8*)qp;
        qf[1] = *(const bf16x8*)(qp + 32);
    }

    f32x4 O[4] = {};
    float m_run = -1e30f, l_run = 0.f;

    for (int mt = 0; mt < SEQM / 64; ++mt) {
        const int m0 = mt * 64;
        unsigned long long mbits = __ballot(mg[m0 + lane] != 0);
        __syncthreads();
        #pragma unroll
        for (int i = 0; i < 2; ++i) {
            int c = tid + (i << 8);
            int r = c >> 3, co = (c & 7) << 3;
            *(bf16x8*)&Ks[r * PKS + co]  = *(const bf16x8*)&kb[(size_t)(m0 + r) * DHEAD + co];
            *(bf16x8*)&Vts[r * PKS + co] = *(const bf16x8*)&vb[(size_t)r * SEQM + m0 + co];
        }
        __syncthreads();

        f32x4 st[4] = {};
        #pragma unroll
        for (int sub = 0; sub < 4; ++sub) {
            #pragma unroll
            for (int c = 0; c < 2; ++c) {
                bf16x8 af = *(const bf16x8*)&Ks[(16 * sub + l15) * PKS + 32 * c + quad * 8];
                st[sub] = __builtin_amdgcn_mfma_f32_16x16x32_bf16(af, qf[c], st[sub], 0, 0, 0);
            }
        }

        float mx = -1e30f;
        float sv[4][4];
        #pragma unroll
        for (int sub = 0; sub < 4; ++sub)
            #pragma unroll
            for (int r = 0; r < 4; ++r) {
                int bit = (int)((mbits >> (16*sub + 4*quad + r)) & 1ULL);
                float xv = bit ? st[sub][r] : -1e30f;
                sv[sub][r] = xv;
                mx = fmaxf(mx, xv);
            }
        mx = fmaxf(mx, __shfl_xor(mx, 16));
        mx = fmaxf(mx, __shfl_xor(mx, 32));
        const float mnew = fmaxf(m_run, mx);
        const float alpha = __expf(m_run - mnew);
        m_run = mnew;

        float psum = 0.f;
        u16 pb[4][4];
        #pragma unroll
        for (int sub = 0; sub < 4; ++sub)
            #pragma unroll
            for (int r = 0; r < 4; ++r) {
                int bit = (int)((mbits >> (16*sub + 4*quad + r)) & 1ULL);
                float p = __expf(sv[sub][r] - mnew);
                p = bit ? p : 0.f;
                psum += p;
                pb[sub][r] = f2bf(p);
            }
        psum += __shfl_xor(psum, 16);
        psum += __shfl_xor(psum, 32);
        l_run = l_run * alpha + psum;

        #pragma unroll
        for (int sub = 0; sub < 4; ++sub) {
            ushort4 w4 = make_ushort4(pb[sub][0], pb[sub][1], pb[sub][2], pb[sub][3]);
            *(ushort4*)&Ps[wave][l15 * PKS + 16 * sub + 4 * quad] = w4;
        }

        float ar[4];
        #pragma unroll
        for (int r = 0; r < 4; ++r) ar[r] = __shfl(alpha, quad * 4 + r);
        #pragma unroll
        for (int sd = 0; sd < 4; ++sd)
            #pragma unroll
            for (int r = 0; r < 4; ++r) O[sd][r] *= ar[r];

        #pragma unroll
        for (int c = 0; c < 2; ++c) {
            bf16x8 pf = *(const bf16x8*)&Ps[wave][l15 * PKS + 32 * c + quad * 8];
            #pragma unroll
            for (int sd = 0; sd < 4; ++sd) {
                bf16x8 vf = *(const bf16x8*)&Vts[(16 * sd + l15) * PKS + 32 * c + quad * 8];
                O[sd] = __builtin_amdgcn_mfma_f32_16x16x32_bf16(pf, vf, O[sd], 0, 0, 0);
            }
        }
    }

    float lr4[4];
    #pragma unroll
    for (int r = 0; r < 4; ++r) lr4[r] = __shfl(l_run, quad * 4 + r);
    #pragma unroll
    for (int r = 0; r < 4; ++r) {
        const int n = n0 + wave * 16 + quad * 4 + r;
        const float inv = 1.f / lr4[r];
        u16* ag = agg + ((size_t)b * SEQN + n) * DIMF + h * DHEAD + l15;
        #pragma unroll
        for (int sd = 0; sd < 4; ++sd)
            ag[16 * sd] = f2bf(O[sd][r] * inv);
    }
}

extern "C" void kernel_launch(void* const* d_in, const int* in_sizes, int n_in,
                              void* d_out, int out_size, void* d_ws, size_t ws_size,
                              hipStream_t stream)
{
    (void)in_sizes; (void)n_in; (void)out_size; (void)ws_size;
    const float* x      = (const float*)d_in[0];
    const float* source = (const float*)d_in[1];
    const int*   mask   = (const int*)  d_in[2];
    const float* Wq = (const float*)d_in[3]; const float* bq = (const float*)d_in[4];
    const float* Wk = (const float*)d_in[5]; const float* bk = (const float*)d_in[6];
    const float* Wv = (const float*)d_in[7]; const float* bv = (const float*)d_in[8];
    const float* Wm = (const float*)d_in[9]; const float* bm = (const float*)d_in[10];
    float* out = (float*)d_out;

    const size_t SZ = (size_t)BATCH * SEQN * DIMF;   // 2,097,152 elems
    const size_t WZ = (size_t)DIMF * DIMF;           //   262,144 elems
    u16* qw   = (u16*)d_ws;          // bf16 [B][H][n][d] (x0.125, +bq)
    u16* kw   = qw  + SZ;            // bf16 [B][H][m][d]
    u16* vtw  = kw  + SZ;            // bf16 [B][H][d][m]
    u16* xb   = vtw + SZ;            // bf16 x   (phase 1-2)  -- aliased:
    u16* aggb = xb;                  // bf16 agg (phase 3-4), disjoint lifetime
    u16* srcb = xb  + SZ;
    u16* wqb  = srcb + SZ;
    u16* wkb  = wqb + WZ;
    u16* wvb  = wkb + WZ;
    u16* wmb  = wvb + WZ;            // total 22 MB

    dim3 gcvt((SZ / 4 + 255) / 256, 6);
    cvt_bf16<<<gcvt, 256, 0, stream>>>(x, source, Wq, Wk, Wv, Wm,
                                       xb, srcb, wqb, wkb, wvb, wmb);

    dim3 gproj(4096 / 128, 512 / 128, 3);   // (32, 4, 3)
    qkv_proj<<<gproj, 256, 0, stream>>>(xb, srcb, wqb, bq, wkb, bk, wvb, bv,
                                        qw, kw, vtw);

    dim3 gattn(SEQN / 64, NHEAD, BATCH);    // (32, 8, 2)
    flash_attn_mfma<<<gattn, 256, 0, stream>>>(qw, kw, vtw, mask, aggb);

    dim3 gout(4096 / 128, 512 / 128);       // (32, 4)
    out_proj<<<gout, 256, 0, stream>>>(aggb, wmb, bm, out);
}